// Round 11
// baseline (3693.421 us; speedup 1.0000x reference)
//
#include <hip/hip_runtime.h>
#include <hip/hip_bf16.h>
#include <cstdint>
#include <cstddef>

// Net: B=256, D=512, L=8, H=8, T=71->64, DH=64.
// Round 11: batch-axis weight reuse. conv_mfma3 / proj64b compute TWO boards
// per wave (mi 0..7, board = mi>>2) so each weight fragment load feeds 2x the
// MFMAs -> L2 weight traffic halved; oct-major block order lets co-resident
// blocks share slabs via L1. Per-layer conv repacks fused (2 -> 1 dispatch).
// ws layout (bytes), total 133,431,296 (unchanged):
//   X71  bf16 @ 0          18,612,224   (embeds; region reused as WcA/WcB after)
//   X64  f32  @ 18,612,224 33,554,432   (residual stream)
//   T1   f32  @ 52,166,656 67,108,864   (conv tmp | qk2 37.2MB + vT 21MB | F1)
//   Wq0  bf16 @119,275,520  1,572,864   (layer-0 QKV weights, [j][d] layout)
//   Wq2  bf16 @120,848,384 12,582,912   (layers 1..8, fragment-slab layout)

typedef float f32x4 __attribute__((ext_vector_type(4)));
typedef short short8 __attribute__((ext_vector_type(8)));

__device__ __forceinline__ float lrelu(float v) { return v > 0.f ? v : 0.2f * v; }
__device__ __forceinline__ __hip_bfloat16 tobf(float v) { return __float2bfloat16(v); }
__device__ __forceinline__ float frombf(__hip_bfloat16 v) { return __bfloat162float(v); }

// ---------------------------------------------------------------------------
// Layer-0 QKV weight repack: emb_qkv (3,8,512,64) f32 -> Wq0[j][d] bf16.
// ---------------------------------------------------------------------------
__global__ __launch_bounds__(256) void repack_qkv_w0(
    const float* __restrict__ emb_qkv, __hip_bfloat16* __restrict__ Wq0)
{
  int o = blockIdx.x * 256 + threadIdx.x;        // < 1536*512
  int j = o >> 9, d = o & 511;
  int n = j >> 9, h = (j >> 6) & 7, dh = j & 63;
  Wq0[o] = tobf(emb_qkv[(((n * 8 + h) * 512 + d) << 6) + dh]);
}

// ---------------------------------------------------------------------------
// Layers 1..8 QKV weight repack into MFMA fragment slabs (validated round 9):
//   Wq2[((((L*8+kc)*2+ks)*96 + nj)*64 + lane)*8 + e] = w[j][d]
//   j = nj*16 + (lane&15), d = kc*64 + ks*32 + (lane>>4)*8 + e.
// ---------------------------------------------------------------------------
__global__ __launch_bounds__(256) void repack_qkv_w2(
    const float* __restrict__ qkvw, __hip_bfloat16* __restrict__ Wq2)
{
  const int t = blockIdx.x * 256 + threadIdx.x;   // < 8*8*2*96*64 = 786432
  const int lane = t & 63;
  const int nj = (t >> 6) % 96;
  int rest = (t >> 6) / 96;
  const int ks = rest & 1;
  const int kc = (rest >> 1) & 7;
  const int L = rest >> 4;
  const int j = nj * 16 + (lane & 15);
  const int d0 = kc * 64 + ks * 32 + (lane >> 4) * 8;
  const int n = j >> 9, h = (j >> 6) & 7, dh = j & 63;
  const float* src = qkvw + ((((size_t)L * 3 + n) * 8 + h) * 512 + d0) * 64 + dh;
  __hip_bfloat16 tmp[8];
  #pragma unroll
  for (int e = 0; e < 8; ++e) tmp[e] = tobf(src[(size_t)e * 64]);
  *(uint4*)&Wq2[(size_t)t * 8] = *(const uint4*)tmp;
}

// ---------------------------------------------------------------------------
// Conv weight repack into fragment slabs (validated round 7). COUT=1024 (co1).
// ---------------------------------------------------------------------------
__global__ __launch_bounds__(256) void repack_conv_w2(
    const float* __restrict__ w, __hip_bfloat16* __restrict__ W2, int COUT)
{
  const int t = blockIdx.x * 256 + threadIdx.x;   // < COUT*64
  if (t >= (COUT << 6)) return;
  const int lr = t & 15;
  const int cbg = (t >> 4) & 63;
  const int oj = t >> 10;
  const int cc = cbg >> 3, ks = (cbg >> 2) & 1, lg = cbg & 3;
  const int o = oj * 16 + lr;
  const int NJ = COUT >> 4;
  const float* src = w + ((size_t)o * 512 + cbg * 8) * 9;
  #pragma unroll
  for (int k = 0; k < 9; ++k) {
    __hip_bfloat16 tmp[8];
    #pragma unroll
    for (int e = 0; e < 8; ++e) tmp[e] = tobf(src[e * 9 + k]);
    size_t di = ((((size_t)cc * 9 + k) * NJ + oj) * 2 + ks) * 512 + (lg * 16 + lr) * 8;
    *(uint4*)&W2[di] = *(const uint4*)tmp;
  }
}

// ---------------------------------------------------------------------------
// Fused per-layer repack: conv1 -> WA and conv2 -> WB in one dispatch.
// ---------------------------------------------------------------------------
__global__ __launch_bounds__(256) void repack_conv_pair(
    const float* __restrict__ w1, const float* __restrict__ w2s,
    __hip_bfloat16* __restrict__ WA, __hip_bfloat16* __restrict__ WB)
{
  int t = blockIdx.x * 256 + threadIdx.x;         // < 2*32768
  const float* w = (t < 32768) ? w1 : w2s;
  __hip_bfloat16* W2 = (t < 32768) ? WA : WB;
  t &= 32767;
  const int lr = t & 15;
  const int cbg = (t >> 4) & 63;
  const int oj = t >> 10;
  const int cc = cbg >> 3, ks = (cbg >> 2) & 1, lg = cbg & 3;
  const int o = oj * 16 + lr;
  const float* src = w + ((size_t)o * 512 + cbg * 8) * 9;
  #pragma unroll
  for (int k = 0; k < 9; ++k) {
    __hip_bfloat16 tmp[8];
    #pragma unroll
    for (int e = 0; e < 8; ++e) tmp[e] = tobf(src[e * 9 + k]);
    size_t di = ((((size_t)cc * 9 + k) * 32 + oj) * 2 + ks) * 512 + (lg * 16 + lr) * 8;
    *(uint4*)&W2[di] = *(const uint4*)tmp;
  }
}

// ---------------------------------------------------------------------------
// Stage 1: embeddings + LayerNorm over T=71 -> X71 bf16 (validated).
// ---------------------------------------------------------------------------
__global__ __launch_bounds__(256) void build_ln_kernel(
    const int* __restrict__ fen, const int* __restrict__ move,
    const float* __restrict__ rank_emb, const float* __restrict__ file_emb,
    const float* __restrict__ fen_emb, const float* __restrict__ move_emb,
    const float* __restrict__ abs_emb, const float* __restrict__ lnw,
    const float* __restrict__ lnb, __hip_bfloat16* __restrict__ X71)
{
  const int gid = blockIdx.x * 256 + threadIdx.x;   // < 256*512
  const int b = gid >> 9, d = gid & 511;
  const int* fb = fen + b * 133;

  float sum = 0.f, sq = 0.f, mu = 0.f, rstd = 0.f;
  #pragma unroll 1
  for (int pass = 0; pass < 2; ++pass) {
    if (pass) {
      mu = sum * (1.f / 71.f);
      float var = sq * (1.f / 71.f) - mu * mu;
      rstd = rsqrtf(var + 1e-5f);
    }
    #pragma unroll 1
    for (int t = 0; t < 71; ++t) {
      float a = abs_emb[t * 512 + d];
      float v;
      if (t < 64) {
        float pos = rank_emb[(t >> 3) * 512 + d] + file_emb[(t & 7) * 512 + d];
        v = 0.5f * (fen_emb[fb[t] * 512 + d] + fen_emb[fb[64 + t] * 512 + d] + pos) + a;
      } else if (t < 69) {
        v = fen_emb[fb[t + 64] * 512 + d] + a;
      } else {
        int j = t - 69;
        int s = move[b * 2 + j];
        float pos = rank_emb[(s >> 3) * 512 + d] + file_emb[(s & 7) * 512 + d];
        v = (pos + move_emb[j * 512 + d]) * 0.58f + a;
      }
      if (pass) X71[(size_t)gid * 71 + t] = tobf((v - mu) * rstd * lnw[t] + lnb[t]);
      else { sum += v; sq += v * v; }
    }
  }
}

// ---------------------------------------------------------------------------
// T=71 embedding QKV projection + fused token-axis RMS (round 8, validated).
// Runs once per forward; uses Wq0 [j][d] layout.
// ---------------------------------------------------------------------------
template <int T, int TP>
__global__ __launch_bounds__(256) void proj71_kernel(
    const __hip_bfloat16* __restrict__ xin, const __hip_bfloat16* __restrict__ Wq,
    const float* __restrict__ nw,
    __hip_bfloat16* __restrict__ qk, __hip_bfloat16* __restrict__ vT)
{
  const int b  = blockIdx.x / 6;
  const int jb = (blockIdx.x % 6) * 256;
  const int tid = threadIdx.x;
  const int lane = tid & 63, wv = tid >> 6;
  const int lr = lane & 15, lg = lane >> 4;

  __shared__ __hip_bfloat16 xt[TP * 72];
  __shared__ __hip_bfloat16 wl[256 * 72];

  constexpr int MI = TP / 16;
  f32x4 acc[MI][4];
  #pragma unroll
  for (int mi = 0; mi < MI; ++mi)
    #pragma unroll
    for (int ni = 0; ni < 4; ++ni) acc[mi][ni] = {0.f, 0.f, 0.f, 0.f};

  for (int c0 = 0; c0 < 512; c0 += 64) {
    for (int i = tid; i < 64 * TP; i += 256) {
      int d = i / TP, t = i - d * TP;
      float v = (t < T) ? lrelu(frombf(xin[((size_t)(b * 512 + c0 + d)) * T + t])) : 0.f;
      xt[t * 72 + d] = tobf(v);
    }
    for (int i = tid; i < 2048; i += 256) {
      int j = i >> 3, cb = i & 7;
      *(uint4*)&wl[j * 72 + cb * 8] =
          *(const uint4*)&Wq[(size_t)(jb + j) * 512 + c0 + cb * 8];
    }
    __syncthreads();
    #pragma unroll
    for (int ks = 0; ks < 2; ++ks) {
      short8 a[MI], bb[4];
      #pragma unroll
      for (int mi = 0; mi < MI; ++mi)
        a[mi] = *(const short8*)&xt[(mi * 16 + lr) * 72 + ks * 32 + lg * 8];
      #pragma unroll
      for (int ni = 0; ni < 4; ++ni)
        bb[ni] = *(const short8*)&wl[(wv * 64 + ni * 16 + lr) * 72 + ks * 32 + lg * 8];
      #pragma unroll
      for (int mi = 0; mi < MI; ++mi)
        #pragma unroll
        for (int ni = 0; ni < 4; ++ni)
          acc[mi][ni] = __builtin_amdgcn_mfma_f32_16x16x32_bf16(
              a[mi], bb[ni], acc[mi][ni], 0, 0, 0);
    }
    __syncthreads();
  }

  #pragma unroll
  for (int ni = 0; ni < 4; ++ni) {
    const int j = jb + wv * 64 + ni * 16 + lr;
    float ss = 0.f;
    #pragma unroll
    for (int mi = 0; mi < MI; ++mi)
      #pragma unroll
      for (int r = 0; r < 4; ++r) ss += acc[mi][ni][r] * acc[mi][ni][r];
    ss += __shfl_xor(ss, 16);
    ss += __shfl_xor(ss, 32);
    const float sc = nw[0] * rsqrtf(ss * (1.f / T) + 1e-6f);
    if (j < 1024) {
      #pragma unroll
      for (int mi = 0; mi < MI; ++mi)
        #pragma unroll
        for (int r = 0; r < 4; ++r) {
          int t = mi * 16 + lg * 4 + r;
          if (t < T)
            qk[((size_t)b * T + t) * 1024 + j] = tobf(acc[mi][ni][r] * sc);
        }
    } else {
      const int jj = j - 1024;
      #pragma unroll
      for (int mi = 0; mi < MI; ++mi)
        #pragma unroll
        for (int r = 0; r < 4; ++r) {
          int t = mi * 16 + lg * 4 + r;   // rows t>=T are true zeros -> valid pad
          vT[((size_t)b * 512 + jj) * TP + t] = tobf(acc[mi][ni][r] * sc);
        }
    }
  }
}

// ---------------------------------------------------------------------------
// T=64 QKV projection, 2 boards per wave (mi 0..7, board = mi>>2). Weights
// direct global->VGPR from fragment slabs (each load feeds 8 MFMA). Block =
// (jseg, board-pair); jseg-major order so co-resident blocks share slabs.
// Fused per-(board,column) token-axis RMS epilogue.
// ---------------------------------------------------------------------------
__global__ __launch_bounds__(256) void proj64b_kernel(
    const float* __restrict__ x,            // (B,512,64) f32
    const __hip_bfloat16* __restrict__ Wq2, // fragment slabs for this layer
    const float* __restrict__ nw,
    __hip_bfloat16* __restrict__ qk, __hip_bfloat16* __restrict__ vT)
{
  const int jseg = blockIdx.x >> 7;          // 0..5
  const int bg   = blockIdx.x & 127;
  const int b0   = bg * 2;
  const int tid = threadIdx.x;
  const int lane = tid & 63, wv = tid >> 6;
  const int lr = lane & 15, lg = lane >> 4;

  __shared__ __hip_bfloat16 xt[2][2][64 * 72];   // [dbuf][board]

  f32x4 acc[8][4];
  #pragma unroll
  for (int mi = 0; mi < 8; ++mi)
    #pragma unroll
    for (int ni = 0; ni < 4; ++ni) acc[mi][ni] = {0.f, 0.f, 0.f, 0.f};

  f32x4 sreg[2][4];
  const int s_d  = tid >> 4;           // d within chunk (+u*16)
  const int s_t4 = (tid & 15) << 2;    // 4 consecutive tokens

  #define PSTAGE_LOAD(kc_)                                                      \
    {                                                                           \
      _Pragma("unroll")                                                         \
      for (int s = 0; s < 2; ++s) {                                             \
        const float* xb_ =                                                      \
            x + ((size_t)(b0 + s) * 512 + (kc_) * 64 + s_d) * 64 + s_t4;        \
        _Pragma("unroll")                                                       \
        for (int u = 0; u < 4; ++u) sreg[s][u] = *(const f32x4*)&xb_[u * 1024]; \
      }                                                                         \
    }
  #define PSTAGE_WRITE(buf_)                                                    \
    {                                                                           \
      _Pragma("unroll")                                                         \
      for (int s = 0; s < 2; ++s)                                               \
        _Pragma("unroll")                                                       \
        for (int u = 0; u < 4; ++u) {                                           \
          _Pragma("unroll")                                                     \
          for (int j = 0; j < 4; ++j)                                           \
            xt[buf_][s][(s_t4 + j) * 72 + s_d + u * 16] =                       \
                tobf(lrelu(sreg[s][u][j]));                                     \
        }                                                                       \
    }

  PSTAGE_LOAD(0);
  PSTAGE_WRITE(0);
  __syncthreads();

  const int njb0 = jseg * 16 + wv * 4;

  for (int kc = 0; kc < 8; ++kc) {
    const int cur = kc & 1;
    if (kc < 7) PSTAGE_LOAD(kc + 1);
    #pragma unroll
    for (int ks = 0; ks < 2; ++ks) {
      short8 bv[4], av[8];
      #pragma unroll
      for (int ni = 0; ni < 4; ++ni)
        bv[ni] = *(const short8*)
            &Wq2[((((size_t)kc * 2 + ks) * 96) + njb0 + ni) * 512 + lane * 8];
      #pragma unroll
      for (int mi = 0; mi < 8; ++mi)
        av[mi] = *(const short8*)
            &xt[cur][mi >> 2][((mi & 3) * 16 + lr) * 72 + ks * 32 + lg * 8];
      #pragma unroll
      for (int mi = 0; mi < 8; ++mi)
        #pragma unroll
        for (int ni = 0; ni < 4; ++ni)
          acc[mi][ni] = __builtin_amdgcn_mfma_f32_16x16x32_bf16(
              av[mi], bv[ni], acc[mi][ni], 0, 0, 0);
    }
    if (kc < 7) PSTAGE_WRITE(cur ^ 1);
    __syncthreads();
  }
  #undef PSTAGE_LOAD
  #undef PSTAGE_WRITE

  // epilogue: per-(board, column) RMS over 64 tokens, then Q/K or V^T writes.
  #pragma unroll
  for (int ni = 0; ni < 4; ++ni) {
    const int j = jseg * 256 + wv * 64 + ni * 16 + lr;
    #pragma unroll
    for (int s = 0; s < 2; ++s) {
      float ss = 0.f;
      #pragma unroll
      for (int m = 0; m < 4; ++m)
        #pragma unroll
        for (int r = 0; r < 4; ++r) ss += acc[s * 4 + m][ni][r] * acc[s * 4 + m][ni][r];
      ss += __shfl_xor(ss, 16);
      ss += __shfl_xor(ss, 32);
      const float sc = nw[0] * rsqrtf(ss * (1.f / 64.f) + 1e-6f);
      const int b = b0 + s;
      if (j < 1024) {
        #pragma unroll
        for (int m = 0; m < 4; ++m)
          #pragma unroll
          for (int r = 0; r < 4; ++r) {
            int t = m * 16 + lg * 4 + r;
            qk[((size_t)b * 64 + t) * 1024 + j] = tobf(acc[s * 4 + m][ni][r] * sc);
          }
      } else {
        const int jj = j - 1024;
        #pragma unroll
        for (int m = 0; m < 4; ++m)
          #pragma unroll
          for (int r = 0; r < 4; ++r) {
            int t = m * 16 + lg * 4 + r;
            vT[((size_t)b * 512 + jj) * 64 + t] = tobf(acc[s * 4 + m][ni][r] * sc);
          }
      }
    }
  }
}

// ---------------------------------------------------------------------------
// MFMA attention per (b,h): S = Q·K^T/8 -> softmax -> O = P·V (+residual).
// Validated round 8.
// ---------------------------------------------------------------------------
template <int T, bool RESBF>
__global__ __launch_bounds__(256) void attn2_kernel(
    const __hip_bfloat16* __restrict__ qk,   // [b][t][1024] RMS'd Q|K
    const __hip_bfloat16* __restrict__ vT,   // [b][jj][TP]  RMS'd V^T
    const void* __restrict__ res, float* __restrict__ out)
{
  constexpr int TP = (T == 71) ? 80 : 64;
  constexpr int TK = (T + 31) / 32;
  constexpr int RS = 72;
  constexpr int PS = TK * 32 + 8;
  constexpr int KR = (T == 71) ? 80 : 64;
  constexpr int SC = (T == 71) ? 82 : 66;
  constexpr int NCF = KR / 16;
  constexpr int NFW = (NCF + 3) / 4;
  constexpr int RANGE = (TK * 32) / 4;

  constexpr int Q_OFF = 0;
  constexpr int K_OFF = Q_OFF + 64 * RS * 2;
  constexpr int V_OFF = K_OFF + KR * RS * 2;
  constexpr int S_OFF = V_OFF + 64 * PS * 2;
  constexpr int BYTES = S_OFF + 64 * SC * 4;
  __shared__ __align__(16) char smem[BYTES];
  __hip_bfloat16* qs = (__hip_bfloat16*)(smem + Q_OFF);
  __hip_bfloat16* ksh = (__hip_bfloat16*)(smem + K_OFF);
  __hip_bfloat16* vs = (__hip_bfloat16*)(smem + V_OFF);
  float* ss = (float*)(smem + S_OFF);
  __hip_bfloat16* ps = (__hip_bfloat16*)(smem + S_OFF);

  const int b = blockIdx.x >> 3, h = blockIdx.x & 7;
  const int tid = threadIdx.x;
  const int lane = tid & 63, wv = tid >> 6;
  const int lr = lane & 15, lg = lane >> 4;

  for (int i = tid; i < BYTES / 16; i += 256) ((uint4*)smem)[i] = uint4{0, 0, 0, 0};
  __syncthreads();

  const __hip_bfloat16* qb = qk + (size_t)b * T * 1024 + h * 64;
  for (int v = tid; v < 512; v += 256) {
    int t = v >> 3, d0 = (v & 7) * 8;
    *(uint4*)&qs[t * RS + d0] = *(const uint4*)&qb[(size_t)t * 1024 + d0];
  }
  for (int v = tid; v < T * 8; v += 256) {
    int t = v >> 3, d0 = (v & 7) * 8;
    *(uint4*)&ksh[t * RS + d0] = *(const uint4*)&qb[(size_t)t * 1024 + 512 + d0];
  }
  constexpr int VV = TP / 8;
  for (int v = tid; v < 64 * VV; v += 256) {
    int dh = v / VV, tc = (v - dh * VV) * 8;
    *(uint4*)&vs[dh * PS + tc] =
        *(const uint4*)&vT[((size_t)b * 512 + h * 64 + dh) * TP + tc];
  }
  __syncthreads();

  // S = Q.K^T * 0.125
  f32x4 sacc[NFW][4];
  #pragma unroll
  for (int fi = 0; fi < NFW; ++fi)
    #pragma unroll
    for (int mi = 0; mi < 4; ++mi) sacc[fi][mi] = {0.f, 0.f, 0.f, 0.f};
  #pragma unroll
  for (int ks2 = 0; ks2 < 2; ++ks2) {
    short8 a[4];
    #pragma unroll
    for (int mi = 0; mi < 4; ++mi)
      a[mi] = *(const short8*)&qs[(mi * 16 + lr) * RS + ks2 * 32 + lg * 8];
    #pragma unroll
    for (int fi = 0; fi < NFW; ++fi) {
      const int f = wv + fi * 4;
      if (f < NCF) {
        short8 bb = *(const short8*)&ksh[(f * 16 + lr) * RS + ks2 * 32 + lg * 8];
        #pragma unroll
        for (int mi = 0; mi < 4; ++mi)
          sacc[fi][mi] = __builtin_amdgcn_mfma_f32_16x16x32_bf16(
              a[mi], bb, sacc[fi][mi], 0, 0, 0);
      }
    }
  }
  #pragma unroll
  for (int fi = 0; fi < NFW; ++fi) {
    const int f = wv + fi * 4;
    if (f < NCF) {
      #pragma unroll
      for (int mi = 0; mi < 4; ++mi)
        #pragma unroll
        for (int r = 0; r < 4; ++r)
          ss[(mi * 16 + lg * 4 + r) * SC + f * 16 + lr] = sacc[fi][mi][r] * 0.125f;
    }
  }
  __syncthreads();

  {
    const int row = tid >> 2, q4 = tid & 3;
    float sv[RANGE];
    float mx = -3.0e38f;
    #pragma unroll
    for (int i = 0; i < RANGE; ++i) {
      int c = q4 * RANGE + i;
      sv[i] = (c < T) ? ss[row * SC + c] : -3.0e38f;
      mx = fmaxf(mx, sv[i]);
    }
    mx = fmaxf(mx, __shfl_xor(mx, 1));
    mx = fmaxf(mx, __shfl_xor(mx, 2));
    float sm = 0.f;
    #pragma unroll
    for (int i = 0; i < RANGE; ++i) {
      int c = q4 * RANGE + i;
      sv[i] = (c < T) ? __expf(sv[i] - mx) : 0.f;
      sm += sv[i];
    }
    sm += __shfl_xor(sm, 1);
    sm += __shfl_xor(sm, 2);
    const float inv = 1.f / sm;
    __syncthreads();
    #pragma unroll
    for (int i = 0; i < RANGE; ++i)
      ps[row * PS + q4 * RANGE + i] = tobf(sv[i] * inv);
  }
  __syncthreads();

  f32x4 oacc[4];
  #pragma unroll
  for (int mi = 0; mi < 4; ++mi) oacc[mi] = {0.f, 0.f, 0.f, 0.f};
  #pragma unroll
  for (int ks2 = 0; ks2 < TK; ++ks2) {
    short8 bb = *(const short8*)&vs[(wv * 16 + lr) * PS + ks2 * 32 + lg * 8];
    #pragma unroll
    for (int mi = 0; mi < 4; ++mi) {
      short8 a = *(const short8*)&ps[(mi * 16 + lr) * PS + ks2 * 32 + lg * 8];
      oacc[mi] = __builtin_amdgcn_mfma_f32_16x16x32_bf16(a, bb, oacc[mi], 0, 0, 0);
    }
  }

  const int dh = wv * 16 + lr;
  const size_t chb = (size_t)b * 512 + h * 64 + dh;
  #pragma unroll
  for (int mi = 0; mi < 4; ++mi) {
    const int t0 = mi * 16 + lg * 4;
    const size_t idx = chb * 64 + t0;
    f32x4 v = oacc[mi];
    if constexpr (RESBF) {
      const __hip_bfloat16* rb = (const __hip_bfloat16*)res + chb * T + t0;
      #pragma unroll
      for (int r = 0; r < 4; ++r) v[r] += frombf(rb[r]);
    } else {
      v += *(const f32x4*)&((const float*)res)[idx];
    }
    *(f32x4*)&out[idx] = v;
  }
}

// ---------------------------------------------------------------------------
// MFMA conv 3x3 SAME on 8x8, CIN=512, 2 boards per wave (mi 0..7, board =
// mi>>2). Block = (oct 128-oc tile, board pair); oct-major order. Weights
// direct global->VGPR; LDS = double-buffered pair of 10x10 boards.
// ---------------------------------------------------------------------------
template <bool RMSOUT, bool RESADD>
__global__ __launch_bounds__(256) void conv_mfma3(
    const float* __restrict__ x,            // (B,512,64) f32
    const __hip_bfloat16* __restrict__ W2,  // fragment slabs
    const float* __restrict__ bias,         // (COUT)
    const float* __restrict__ nw,           // scalar rms weight (RMSOUT)
    const float* __restrict__ res,          // (B,COUT,64) f32 (RESADD)
    float* __restrict__ out,                // (B,COUT,64) f32
    int COUT)
{
  const int oct = blockIdx.x >> 7;           // oc tile of 128
  const int bg  = blockIdx.x & 127;
  const int b0  = bg * 2;
  const int NJ = COUT >> 4;
  const int tid = threadIdx.x;
  const int lane = tid & 63, wv = tid >> 6;
  const int lr = lane & 15, lg = lane >> 4;

  __shared__ __hip_bfloat16 xt[2][2][100 * 72];   // [dbuf][board] 10x10 boards

  f32x4 acc[8][2];
  #pragma unroll
  for (int mi = 0; mi < 8; ++mi)
    #pragma unroll
    for (int ni = 0; ni < 2; ++ni) acc[mi][ni] = {0.f, 0.f, 0.f, 0.f};

  for (int i = tid; i < 3600; i += 256) ((uint4*)xt)[i] = uint4{0, 0, 0, 0};

  f32x4 sreg[2][4];
  const int s_ci = tid >> 4;
  const int s_p4 = (tid & 15) << 2;
  const int s_row = (((s_p4 >> 3) + 1) * 10 + (s_p4 & 7) + 1) * 72;

  #define STAGE_LOAD(cc_)                                                       \
    {                                                                           \
      _Pragma("unroll")                                                         \
      for (int s = 0; s < 2; ++s) {                                             \
        const float* xb_ =                                                      \
            x + ((size_t)(b0 + s) * 512 + (cc_) * 64 + s_ci) * 64 + s_p4;       \
        _Pragma("unroll")                                                       \
        for (int u = 0; u < 4; ++u) sreg[s][u] = *(const f32x4*)&xb_[u * 1024]; \
      }                                                                         \
    }
  #define STAGE_WRITE(buf_)                                                     \
    {                                                                           \
      _Pragma("unroll")                                                         \
      for (int s = 0; s < 2; ++s)                                               \
        _Pragma("unroll")                                                       \
        for (int u = 0; u < 4; ++u) {                                           \
          _Pragma("unroll")                                                     \
          for (int j = 0; j < 4; ++j)                                           \
            xt[buf_][s][s_row + j * 72 + s_ci + u * 16] =                       \
                tobf(lrelu(sreg[s][u][j]));                                     \
        }                                                                       \
    }

  STAGE_LOAD(0);
  __syncthreads();            // zero-init visible before interior writes
  STAGE_WRITE(0);
  __syncthreads();

  const int njb = oct * 8 + wv * 2;

  for (int cc = 0; cc < 8; ++cc) {
    const int cur = cc & 1;
    if (cc < 7) STAGE_LOAD(cc + 1);

    #pragma unroll
    for (int k = 0; k < 9; ++k) {
      const int dy = k / 3 - 1, dx = k - (k / 3) * 3 - 1;
      const int ii0 = (lr >> 3) + dy + 1;
      const int jj0 = (lr & 7) + dx + 1;
      short8 bv[2][2], av[2][8];
      #pragma unroll
      for (int ni = 0; ni < 2; ++ni)
        #pragma unroll
        for (int ks = 0; ks < 2; ++ks)
          bv[ks][ni] = *(const short8*)
              &W2[((((size_t)(cc * 9 + k)) * NJ + njb + ni) * 2 + ks) * 512 + lane * 8];
      #pragma unroll
      for (int ks = 0; ks < 2; ++ks)
        #pragma unroll
        for (int mi = 0; mi < 8; ++mi)
          av[ks][mi] = *(const short8*)
              &xt[cur][mi >> 2][((ii0 + (mi & 3) * 2) * 10 + jj0) * 72 + ks * 32 + lg * 8];
      #pragma unroll
      for (int ks = 0; ks < 2; ++ks)
        #pragma unroll
        for (int mi = 0; mi < 8; ++mi)
          #pragma unroll
          for (int ni = 0; ni < 2; ++ni)
            acc[mi][ni] = __builtin_amdgcn_mfma_f32_16x16x32_bf16(
                av[ks][mi], bv[ks][ni], acc[mi][ni], 0, 0, 0);
    }
    if (cc < 7) STAGE_WRITE(cur ^ 1);
    __syncthreads();
  }
  #undef STAGE_LOAD
  #undef STAGE_WRITE

  // epilogue: +bias, per-board spatial RMS (fold lg via shfl 16/32), +res.
  #pragma unroll
  for (int ni = 0; ni < 2; ++ni) {
    const int o = oct * 128 + wv * 32 + ni * 16 + lr;
    const float bvs = bias[o];
    #pragma unroll
    for (int s = 0; s < 2; ++s) {
      float sc = 1.f;
      if constexpr (RMSOUT) {
        float ssq = 0.f;
        #pragma unroll
        for (int m = 0; m < 4; ++m)
          #pragma unroll
          for (int r = 0; r < 4; ++r) {
            float v = acc[s * 4 + m][ni][r] + bvs;
            ssq += v * v;
          }
        ssq += __shfl_xor(ssq, 16);
        ssq += __shfl_xor(ssq, 32);
        sc = nw[0] * rsqrtf(ssq * (1.f / 64.f) + 1e-6f);
      }
      #pragma unroll
      for (int m = 0; m < 4; ++m) {
        size_t idx = ((size_t)(b0 + s) * COUT + o) * 64 + m * 16 + lg * 4;
        f32x4 v;
        #pragma unroll
        for (int r = 0; r < 4; ++r) v[r] = (acc[s * 4 + m][ni][r] + bvs) * sc;
        if constexpr (RESADD) v += *(const f32x4*)&res[idx];
        *(f32x4*)&out[idx] = v;
      }
    }
  }
}

// ---------------------------------------------------------------------------
// Final VALID 8x8 conv: out[b] = sum_{c,p} lrelu(F1[b,c,p]) * w[c,p] + bias.
// ---------------------------------------------------------------------------
__global__ __launch_bounds__(256) void co2_kernel(
    const float* __restrict__ xf, const float* __restrict__ w,
    const float* __restrict__ cb, float* __restrict__ out)
{
  const int b = blockIdx.x, tid = threadIdx.x;
  const float* xb = xf + (size_t)b * 65536;
  float acc = 0.f;
  for (int i = tid; i < 65536; i += 256)
    acc += lrelu(xb[i]) * w[i];
  #pragma unroll
  for (int off = 32; off; off >>= 1) acc += __shfl_down(acc, off);
  __shared__ float red[4];
  if ((tid & 63) == 0) red[tid >> 6] = acc;
  __syncthreads();
  if (tid == 0) out[b] = red[0] + red[1] + red[2] + red[3] + cb[0];
}

// ---------------------------------------------------------------------------
extern "C" void kernel_launch(void* const* d_in, const int* in_sizes, int n_in,
                              void* d_out, int out_size, void* d_ws, size_t ws_size,
                              hipStream_t stream)
{
  const int*   fen        = (const int*)d_in[0];
  const int*   move       = (const int*)d_in[1];
  const float* rank_emb   = (const float*)d_in[2];
  const float* file_emb   = (const float*)d_in[3];
  const float* fen_emb    = (const float*)d_in[4];
  const float* move_emb   = (const float*)d_in[5];
  const float* abs_emb    = (const float*)d_in[6];
  const float* ln_w       = (const float*)d_in[7];
  const float* ln_b       = (const float*)d_in[8];
  const float* emb_qkv    = (const float*)d_in[9];
  const float* emb_norm_w = (const float*)d_in[10];
  const float* qkvw_in    = (const float*)d_in[11];
  const float* mha_norm_w = (const float*)d_in[12];
  const float* conv1_w    = (const float*)d_in[13];
  const float* conv1_b    = (const float*)d_in[14];
  const float* conv2_w    = (const float*)d_in[15];
  const float* conv2_b    = (const float*)d_in[16];
  const float* cb_norm_w  = (const float*)d_in[17];
  const float* out_norm_w = (const float*)d_in[18];
  const float* co1_w      = (const float*)d_in[19];
  const float* co1_b      = (const float*)d_in[20];
  const float* co2_w      = (const float*)d_in[21];
  const float* co2_b      = (const float*)d_in[22];
  float* out = (float*)d_out;

  char* base = (char*)d_ws;
  __hip_bfloat16* X71 = (__hip_bfloat16*)base;                       // 18,612,224 B
  float* X64 = (float*)(base + 18612224);                            // 33,554,432 B
  float* T1  = (float*)(base + 18612224 + 33554432);                 // 67,108,864 B
  __hip_bfloat16* Wq0 = (__hip_bfloat16*)(base + 119275520);         //  1,572,864 B
  __hip_bfloat16* Wq2 = (__hip_bfloat16*)(base + 120848384);         // 12,582,912 B
  __hip_bfloat16* qk2 = (__hip_bfloat16*)T1;                         // <=37,224,448 B
  __hip_bfloat16* vTb = (__hip_bfloat16*)((char*)T1 + 37224448);     // <=20,971,520 B
  float* F1 = T1;                                                    // co1 out, 67MB
  __hip_bfloat16* WcA = (__hip_bfloat16*)base;                 // up to 9,437,184 B (co1)
  __hip_bfloat16* WcB = (__hip_bfloat16*)(base + 4718592);     // 4,718,592 B

  // one-time QKV weight repacks
  repack_qkv_w0<<<3072, 256, 0, stream>>>(emb_qkv, Wq0);
  repack_qkv_w2<<<3072, 256, 0, stream>>>(qkvw_in, Wq2);

  // embeddings + layernorm -> X71 (bf16)
  build_ln_kernel<<<512, 256, 0, stream>>>(fen, move, rank_emb, file_emb,
                                           fen_emb, move_emb, abs_emb,
                                           ln_w, ln_b, X71);
  // embedding MHA (T=71): proj(+RMS) -> attn2 (residual = X71[:, :, :64])
  proj71_kernel<71, 80><<<1536, 256, 0, stream>>>(X71, Wq0, emb_norm_w, qk2, vTb);
  attn2_kernel<71, true><<<2048, 256, 0, stream>>>(qk2, vTb, X71, X64);

  for (int l = 0; l < 8; ++l) {
    repack_conv_pair<<<256, 256, 0, stream>>>(conv1_w + (size_t)l * 512 * 512 * 9,
                                              conv2_w + (size_t)l * 512 * 512 * 9,
                                              WcA, WcB);
    conv_mfma3<true, false><<<512, 256, 0, stream>>>(X64, WcA, conv1_b + l * 512,
                                                     cb_norm_w + l, nullptr, T1, 512);
    conv_mfma3<false, true><<<512, 256, 0, stream>>>(T1, WcB, conv2_b + l * 512,
                                                     nullptr, X64, X64, 512);
    // MHA (T=64)
    proj64b_kernel<<<768, 256, 0, stream>>>(X64, Wq2 + (size_t)l * 786432,
                                            mha_norm_w + l, qk2, vTb);
    attn2_kernel<64, false><<<2048, 256, 0, stream>>>(qk2, vTb, X64, X64);
  }

  // head: co1 (512->1024 SAME, RMS fused) -> co2 (VALID 8x8 -> scalar)
  repack_conv_w2<<<256, 256, 0, stream>>>(co1_w, WcA, 1024);
  conv_mfma3<true, false><<<1024, 256, 0, stream>>>(X64, WcA, co1_b,
                                                    out_norm_w, nullptr, F1, 1024);
  co2_kernel<<<256, 256, 0, stream>>>(F1, co2_w, co2_b, out);
}

// Round 12
// 2647.115 us; speedup vs baseline: 1.3953x; 1.3953x over previous
//
#include <hip/hip_runtime.h>
#include <hip/hip_bf16.h>
#include <cstdint>
#include <cstddef>

// Net: B=256, D=512, L=8, H=8, T=71->64, DH=64.
// Round 12: revert to round-10 validated conv_mfma2/proj64 structure (round-11
// 2-board variants regressed: occupancy 25%->12%, LDS conflicts 2x, HBM
// refetch up). New lever, numerics-identical: conv-phase activations flow as
// pre-lrelu'd bf16 board-transposed tensors (Xc written by attn2 epilogue,
// Tc written by conv1 epilogue) -> conv staging becomes coalesced 16B copies
// with conflict-free ds_write_b128, and conv-phase HBM bytes halve.
// ws layout (bytes), total 133,431,296:
//   X71  bf16 @ 0          18,612,224   (embeds; region reused as WcA/WcB after)
//   X64  f32  @ 18,612,224 33,554,432   (residual stream master, f32 always)
//   T1   region @ 52,166,656 67,108,864:
//     embedding: qk71 [0,37.2M) | vT71 [37.2M,58.2M)
//     layer loop: Tc [0,16.8M) (conv) / qk64 [0,33.5M)+vT64 [33.5M,50.3M)
//                 (proj/attn) | Xc [50.3M,67.1M) (persistent within layer)
//     head: F1 f32 [0,67.1M)
//   Wq0  bf16 @119,275,520  1,572,864
//   Wq2  bf16 @120,848,384 12,582,912

typedef float f32x4 __attribute__((ext_vector_type(4)));
typedef short short8 __attribute__((ext_vector_type(8)));

__device__ __forceinline__ float lrelu(float v) { return v > 0.f ? v : 0.2f * v; }
__device__ __forceinline__ __hip_bfloat16 tobf(float v) { return __float2bfloat16(v); }
__device__ __forceinline__ float frombf(__hip_bfloat16 v) { return __bfloat162float(v); }

// ---------------------------------------------------------------------------
// Layer-0 QKV weight repack: emb_qkv (3,8,512,64) f32 -> Wq0[j][d] bf16.
// ---------------------------------------------------------------------------
__global__ __launch_bounds__(256) void repack_qkv_w0(
    const float* __restrict__ emb_qkv, __hip_bfloat16* __restrict__ Wq0)
{
  int o = blockIdx.x * 256 + threadIdx.x;        // < 1536*512
  int j = o >> 9, d = o & 511;
  int n = j >> 9, h = (j >> 6) & 7, dh = j & 63;
  Wq0[o] = tobf(emb_qkv[(((n * 8 + h) * 512 + d) << 6) + dh]);
}

// ---------------------------------------------------------------------------
// Layers 1..8 QKV weight repack into MFMA fragment slabs (validated round 9).
// ---------------------------------------------------------------------------
__global__ __launch_bounds__(256) void repack_qkv_w2(
    const float* __restrict__ qkvw, __hip_bfloat16* __restrict__ Wq2)
{
  const int t = blockIdx.x * 256 + threadIdx.x;   // < 786432
  const int lane = t & 63;
  const int nj = (t >> 6) % 96;
  int rest = (t >> 6) / 96;
  const int ks = rest & 1;
  const int kc = (rest >> 1) & 7;
  const int L = rest >> 4;
  const int j = nj * 16 + (lane & 15);
  const int d0 = kc * 64 + ks * 32 + (lane >> 4) * 8;
  const int n = j >> 9, h = (j >> 6) & 7, dh = j & 63;
  const float* src = qkvw + ((((size_t)L * 3 + n) * 8 + h) * 512 + d0) * 64 + dh;
  __hip_bfloat16 tmp[8];
  #pragma unroll
  for (int e = 0; e < 8; ++e) tmp[e] = tobf(src[(size_t)e * 64]);
  *(uint4*)&Wq2[(size_t)t * 8] = *(const uint4*)tmp;
}

// ---------------------------------------------------------------------------
// Conv weight repack into fragment slabs (validated round 7). Used for co1.
// ---------------------------------------------------------------------------
__global__ __launch_bounds__(256) void repack_conv_w2(
    const float* __restrict__ w, __hip_bfloat16* __restrict__ W2, int COUT)
{
  const int t = blockIdx.x * 256 + threadIdx.x;   // < COUT*64
  if (t >= (COUT << 6)) return;
  const int lr = t & 15;
  const int cbg = (t >> 4) & 63;
  const int oj = t >> 10;
  const int cc = cbg >> 3, ks = (cbg >> 2) & 1, lg = cbg & 3;
  const int o = oj * 16 + lr;
  const int NJ = COUT >> 4;
  const float* src = w + ((size_t)o * 512 + cbg * 8) * 9;
  #pragma unroll
  for (int k = 0; k < 9; ++k) {
    __hip_bfloat16 tmp[8];
    #pragma unroll
    for (int e = 0; e < 8; ++e) tmp[e] = tobf(src[e * 9 + k]);
    size_t di = ((((size_t)cc * 9 + k) * NJ + oj) * 2 + ks) * 512 + (lg * 16 + lr) * 8;
    *(uint4*)&W2[di] = *(const uint4*)tmp;
  }
}

// ---------------------------------------------------------------------------
// Fused per-layer repack: conv1 -> WA and conv2 -> WB (validated round 11).
// ---------------------------------------------------------------------------
__global__ __launch_bounds__(256) void repack_conv_pair(
    const float* __restrict__ w1, const float* __restrict__ w2s,
    __hip_bfloat16* __restrict__ WA, __hip_bfloat16* __restrict__ WB)
{
  int t = blockIdx.x * 256 + threadIdx.x;         // < 2*32768
  const float* w = (t < 32768) ? w1 : w2s;
  __hip_bfloat16* W2 = (t < 32768) ? WA : WB;
  t &= 32767;
  const int lr = t & 15;
  const int cbg = (t >> 4) & 63;
  const int oj = t >> 10;
  const int cc = cbg >> 3, ks = (cbg >> 2) & 1, lg = cbg & 3;
  const int o = oj * 16 + lr;
  const float* src = w + ((size_t)o * 512 + cbg * 8) * 9;
  #pragma unroll
  for (int k = 0; k < 9; ++k) {
    __hip_bfloat16 tmp[8];
    #pragma unroll
    for (int e = 0; e < 8; ++e) tmp[e] = tobf(src[e * 9 + k]);
    size_t di = ((((size_t)cc * 9 + k) * 32 + oj) * 2 + ks) * 512 + (lg * 16 + lr) * 8;
    *(uint4*)&W2[di] = *(const uint4*)tmp;
  }
}

// ---------------------------------------------------------------------------
// Stage 1: embeddings + LayerNorm over T=71 -> X71 bf16 (validated).
// ---------------------------------------------------------------------------
__global__ __launch_bounds__(256) void build_ln_kernel(
    const int* __restrict__ fen, const int* __restrict__ move,
    const float* __restrict__ rank_emb, const float* __restrict__ file_emb,
    const float* __restrict__ fen_emb, const float* __restrict__ move_emb,
    const float* __restrict__ abs_emb, const float* __restrict__ lnw,
    const float* __restrict__ lnb, __hip_bfloat16* __restrict__ X71)
{
  const int gid = blockIdx.x * 256 + threadIdx.x;   // < 256*512
  const int b = gid >> 9, d = gid & 511;
  const int* fb = fen + b * 133;

  float sum = 0.f, sq = 0.f, mu = 0.f, rstd = 0.f;
  #pragma unroll 1
  for (int pass = 0; pass < 2; ++pass) {
    if (pass) {
      mu = sum * (1.f / 71.f);
      float var = sq * (1.f / 71.f) - mu * mu;
      rstd = rsqrtf(var + 1e-5f);
    }
    #pragma unroll 1
    for (int t = 0; t < 71; ++t) {
      float a = abs_emb[t * 512 + d];
      float v;
      if (t < 64) {
        float pos = rank_emb[(t >> 3) * 512 + d] + file_emb[(t & 7) * 512 + d];
        v = 0.5f * (fen_emb[fb[t] * 512 + d] + fen_emb[fb[64 + t] * 512 + d] + pos) + a;
      } else if (t < 69) {
        v = fen_emb[fb[t + 64] * 512 + d] + a;
      } else {
        int j = t - 69;
        int s = move[b * 2 + j];
        float pos = rank_emb[(s >> 3) * 512 + d] + file_emb[(s & 7) * 512 + d];
        v = (pos + move_emb[j * 512 + d]) * 0.58f + a;
      }
      if (pass) X71[(size_t)gid * 71 + t] = tobf((v - mu) * rstd * lnw[t] + lnb[t]);
      else { sum += v; sq += v * v; }
    }
  }
}

// ---------------------------------------------------------------------------
// T=71 embedding QKV projection + fused token-axis RMS (validated round 8).
// ---------------------------------------------------------------------------
template <int T, int TP>
__global__ __launch_bounds__(256) void proj71_kernel(
    const __hip_bfloat16* __restrict__ xin, const __hip_bfloat16* __restrict__ Wq,
    const float* __restrict__ nw,
    __hip_bfloat16* __restrict__ qk, __hip_bfloat16* __restrict__ vT)
{
  const int b  = blockIdx.x / 6;
  const int jb = (blockIdx.x % 6) * 256;
  const int tid = threadIdx.x;
  const int lane = tid & 63, wv = tid >> 6;
  const int lr = lane & 15, lg = lane >> 4;

  __shared__ __hip_bfloat16 xt[TP * 72];
  __shared__ __hip_bfloat16 wl[256 * 72];

  constexpr int MI = TP / 16;
  f32x4 acc[MI][4];
  #pragma unroll
  for (int mi = 0; mi < MI; ++mi)
    #pragma unroll
    for (int ni = 0; ni < 4; ++ni) acc[mi][ni] = {0.f, 0.f, 0.f, 0.f};

  for (int c0 = 0; c0 < 512; c0 += 64) {
    for (int i = tid; i < 64 * TP; i += 256) {
      int d = i / TP, t = i - d * TP;
      float v = (t < T) ? lrelu(frombf(xin[((size_t)(b * 512 + c0 + d)) * T + t])) : 0.f;
      xt[t * 72 + d] = tobf(v);
    }
    for (int i = tid; i < 2048; i += 256) {
      int j = i >> 3, cb = i & 7;
      *(uint4*)&wl[j * 72 + cb * 8] =
          *(const uint4*)&Wq[(size_t)(jb + j) * 512 + c0 + cb * 8];
    }
    __syncthreads();
    #pragma unroll
    for (int ks = 0; ks < 2; ++ks) {
      short8 a[MI], bb[4];
      #pragma unroll
      for (int mi = 0; mi < MI; ++mi)
        a[mi] = *(const short8*)&xt[(mi * 16 + lr) * 72 + ks * 32 + lg * 8];
      #pragma unroll
      for (int ni = 0; ni < 4; ++ni)
        bb[ni] = *(const short8*)&wl[(wv * 64 + ni * 16 + lr) * 72 + ks * 32 + lg * 8];
      #pragma unroll
      for (int mi = 0; mi < MI; ++mi)
        #pragma unroll
        for (int ni = 0; ni < 4; ++ni)
          acc[mi][ni] = __builtin_amdgcn_mfma_f32_16x16x32_bf16(
              a[mi], bb[ni], acc[mi][ni], 0, 0, 0);
    }
    __syncthreads();
  }

  #pragma unroll
  for (int ni = 0; ni < 4; ++ni) {
    const int j = jb + wv * 64 + ni * 16 + lr;
    float ss = 0.f;
    #pragma unroll
    for (int mi = 0; mi < MI; ++mi)
      #pragma unroll
      for (int r = 0; r < 4; ++r) ss += acc[mi][ni][r] * acc[mi][ni][r];
    ss += __shfl_xor(ss, 16);
    ss += __shfl_xor(ss, 32);
    const float sc = nw[0] * rsqrtf(ss * (1.f / T) + 1e-6f);
    if (j < 1024) {
      #pragma unroll
      for (int mi = 0; mi < MI; ++mi)
        #pragma unroll
        for (int r = 0; r < 4; ++r) {
          int t = mi * 16 + lg * 4 + r;
          if (t < T)
            qk[((size_t)b * T + t) * 1024 + j] = tobf(acc[mi][ni][r] * sc);
        }
    } else {
      const int jj = j - 1024;
      #pragma unroll
      for (int mi = 0; mi < MI; ++mi)
        #pragma unroll
        for (int r = 0; r < 4; ++r) {
          int t = mi * 16 + lg * 4 + r;   // rows t>=T are true zeros -> valid pad
          vT[((size_t)b * 512 + jj) * TP + t] = tobf(acc[mi][ni][r] * sc);
        }
    }
  }
}

// ---------------------------------------------------------------------------
// T=64 QKV projection (validated round 9/10): fragment-slab weights direct
// global->VGPR, double-buffered activation LDS, fused token-axis RMS.
// ---------------------------------------------------------------------------
__global__ __launch_bounds__(256) void proj64_kernel(
    const float* __restrict__ x,            // (B,512,64) f32
    const __hip_bfloat16* __restrict__ Wq2, // fragment slabs for this layer
    const float* __restrict__ nw,
    __hip_bfloat16* __restrict__ qk, __hip_bfloat16* __restrict__ vT)
{
  const int b    = blockIdx.x / 6;
  const int jseg = blockIdx.x % 6;
  const int tid = threadIdx.x;
  const int lane = tid & 63, wv = tid >> 6;
  const int lr = lane & 15, lg = lane >> 4;

  __shared__ __hip_bfloat16 xt[2][64 * 72];

  f32x4 acc[4][4];
  #pragma unroll
  for (int mi = 0; mi < 4; ++mi)
    #pragma unroll
    for (int ni = 0; ni < 4; ++ni) acc[mi][ni] = {0.f, 0.f, 0.f, 0.f};

  f32x4 sreg[4];
  const int s_d  = tid >> 4;
  const int s_t4 = (tid & 15) << 2;

  #define PSTAGE_LOAD(kc_)                                                    \
    {                                                                         \
      const float* xb_ = x + ((size_t)b * 512 + (kc_) * 64 + s_d) * 64 + s_t4; \
      _Pragma("unroll")                                                       \
      for (int u = 0; u < 4; ++u) sreg[u] = *(const f32x4*)&xb_[u * 1024];    \
    }
  #define PSTAGE_WRITE(buf_)                                                  \
    {                                                                         \
      _Pragma("unroll")                                                       \
      for (int u = 0; u < 4; ++u) {                                           \
        _Pragma("unroll")                                                     \
        for (int j = 0; j < 4; ++j)                                           \
          xt[buf_][(s_t4 + j) * 72 + s_d + u * 16] = tobf(lrelu(sreg[u][j])); \
      }                                                                       \
    }

  PSTAGE_LOAD(0);
  PSTAGE_WRITE(0);
  __syncthreads();

  const int njb0 = jseg * 16 + wv * 4;

  for (int kc = 0; kc < 8; ++kc) {
    const int cur = kc & 1;
    if (kc < 7) PSTAGE_LOAD(kc + 1);
    const __hip_bfloat16* xb = xt[cur];
    #pragma unroll
    for (int ks = 0; ks < 2; ++ks) {
      short8 bv[4], av[4];
      #pragma unroll
      for (int ni = 0; ni < 4; ++ni)
        bv[ni] = *(const short8*)
            &Wq2[((((size_t)kc * 2 + ks) * 96) + njb0 + ni) * 512 + lane * 8];
      #pragma unroll
      for (int mi = 0; mi < 4; ++mi)
        av[mi] = *(const short8*)&xb[(mi * 16 + lr) * 72 + ks * 32 + lg * 8];
      #pragma unroll
      for (int mi = 0; mi < 4; ++mi)
        #pragma unroll
        for (int ni = 0; ni < 4; ++ni)
          acc[mi][ni] = __builtin_amdgcn_mfma_f32_16x16x32_bf16(
              av[mi], bv[ni], acc[mi][ni], 0, 0, 0);
    }
    if (kc < 7) PSTAGE_WRITE(cur ^ 1);
    __syncthreads();
  }
  #undef PSTAGE_LOAD
  #undef PSTAGE_WRITE

  #pragma unroll
  for (int ni = 0; ni < 4; ++ni) {
    const int j = jseg * 256 + wv * 64 + ni * 16 + lr;
    float ss = 0.f;
    #pragma unroll
    for (int mi = 0; mi < 4; ++mi)
      #pragma unroll
      for (int r = 0; r < 4; ++r) ss += acc[mi][ni][r] * acc[mi][ni][r];
    ss += __shfl_xor(ss, 16);
    ss += __shfl_xor(ss, 32);
    const float sc = nw[0] * rsqrtf(ss * (1.f / 64.f) + 1e-6f);
    if (j < 1024) {
      #pragma unroll
      for (int mi = 0; mi < 4; ++mi)
        #pragma unroll
        for (int r = 0; r < 4; ++r) {
          int t = mi * 16 + lg * 4 + r;
          qk[((size_t)b * 64 + t) * 1024 + j] = tobf(acc[mi][ni][r] * sc);
        }
    } else {
      const int jj = j - 1024;
      #pragma unroll
      for (int mi = 0; mi < 4; ++mi)
        #pragma unroll
        for (int r = 0; r < 4; ++r) {
          int t = mi * 16 + lg * 4 + r;
          vT[((size_t)b * 512 + jj) * 64 + t] = tobf(acc[mi][ni][r] * sc);
        }
    }
  }
}

// ---------------------------------------------------------------------------
// MFMA attention per (b,h) (validated round 8) + optional Xc write:
// Xc[b][cell][ch] = tobf(lrelu(res + PV)) — the exact value the next conv's
// staging would have computed from f32 X64 (bit-identical numerics).
// ---------------------------------------------------------------------------
template <int T, bool RESBF, bool WRITEXC>
__global__ __launch_bounds__(256) void attn2_kernel(
    const __hip_bfloat16* __restrict__ qk,   // [b][t][1024] RMS'd Q|K
    const __hip_bfloat16* __restrict__ vT,   // [b][jj][TP]  RMS'd V^T
    const void* __restrict__ res, float* __restrict__ out,
    __hip_bfloat16* __restrict__ xcout)
{
  constexpr int TP = (T == 71) ? 80 : 64;
  constexpr int TK = (T + 31) / 32;
  constexpr int RS = 72;
  constexpr int PS = TK * 32 + 8;
  constexpr int KR = (T == 71) ? 80 : 64;
  constexpr int SC = (T == 71) ? 82 : 66;
  constexpr int NCF = KR / 16;
  constexpr int NFW = (NCF + 3) / 4;
  constexpr int RANGE = (TK * 32) / 4;

  constexpr int Q_OFF = 0;
  constexpr int K_OFF = Q_OFF + 64 * RS * 2;
  constexpr int V_OFF = K_OFF + KR * RS * 2;
  constexpr int S_OFF = V_OFF + 64 * PS * 2;
  constexpr int BYTES = S_OFF + 64 * SC * 4;
  __shared__ __align__(16) char smem[BYTES];
  __hip_bfloat16* qs = (__hip_bfloat16*)(smem + Q_OFF);
  __hip_bfloat16* ksh = (__hip_bfloat16*)(smem + K_OFF);
  __hip_bfloat16* vs = (__hip_bfloat16*)(smem + V_OFF);
  float* ss = (float*)(smem + S_OFF);
  __hip_bfloat16* ps = (__hip_bfloat16*)(smem + S_OFF);

  const int b = blockIdx.x >> 3, h = blockIdx.x & 7;
  const int tid = threadIdx.x;
  const int lane = tid & 63, wv = tid >> 6;
  const int lr = lane & 15, lg = lane >> 4;

  for (int i = tid; i < BYTES / 16; i += 256) ((uint4*)smem)[i] = uint4{0, 0, 0, 0};
  __syncthreads();

  const __hip_bfloat16* qb = qk + (size_t)b * T * 1024 + h * 64;
  for (int v = tid; v < 512; v += 256) {
    int t = v >> 3, d0 = (v & 7) * 8;
    *(uint4*)&qs[t * RS + d0] = *(const uint4*)&qb[(size_t)t * 1024 + d0];
  }
  for (int v = tid; v < T * 8; v += 256) {
    int t = v >> 3, d0 = (v & 7) * 8;
    *(uint4*)&ksh[t * RS + d0] = *(const uint4*)&qb[(size_t)t * 1024 + 512 + d0];
  }
  constexpr int VV = TP / 8;
  for (int v = tid; v < 64 * VV; v += 256) {
    int dh = v / VV, tc = (v - dh * VV) * 8;
    *(uint4*)&vs[dh * PS + tc] =
        *(const uint4*)&vT[((size_t)b * 512 + h * 64 + dh) * TP + tc];
  }
  __syncthreads();

  // S = Q.K^T * 0.125
  f32x4 sacc[NFW][4];
  #pragma unroll
  for (int fi = 0; fi < NFW; ++fi)
    #pragma unroll
    for (int mi = 0; mi < 4; ++mi) sacc[fi][mi] = {0.f, 0.f, 0.f, 0.f};
  #pragma unroll
  for (int ks2 = 0; ks2 < 2; ++ks2) {
    short8 a[4];
    #pragma unroll
    for (int mi = 0; mi < 4; ++mi)
      a[mi] = *(const short8*)&qs[(mi * 16 + lr) * RS + ks2 * 32 + lg * 8];
    #pragma unroll
    for (int fi = 0; fi < NFW; ++fi) {
      const int f = wv + fi * 4;
      if (f < NCF) {
        short8 bb = *(const short8*)&ksh[(f * 16 + lr) * RS + ks2 * 32 + lg * 8];
        #pragma unroll
        for (int mi = 0; mi < 4; ++mi)
          sacc[fi][mi] = __builtin_amdgcn_mfma_f32_16x16x32_bf16(
              a[mi], bb, sacc[fi][mi], 0, 0, 0);
      }
    }
  }
  #pragma unroll
  for (int fi = 0; fi < NFW; ++fi) {
    const int f = wv + fi * 4;
    if (f < NCF) {
      #pragma unroll
      for (int mi = 0; mi < 4; ++mi)
        #pragma unroll
        for (int r = 0; r < 4; ++r)
          ss[(mi * 16 + lg * 4 + r) * SC + f * 16 + lr] = sacc[fi][mi][r] * 0.125f;
    }
  }
  __syncthreads();

  {
    const int row = tid >> 2, q4 = tid & 3;
    float sv[RANGE];
    float mx = -3.0e38f;
    #pragma unroll
    for (int i = 0; i < RANGE; ++i) {
      int c = q4 * RANGE + i;
      sv[i] = (c < T) ? ss[row * SC + c] : -3.0e38f;
      mx = fmaxf(mx, sv[i]);
    }
    mx = fmaxf(mx, __shfl_xor(mx, 1));
    mx = fmaxf(mx, __shfl_xor(mx, 2));
    float sm = 0.f;
    #pragma unroll
    for (int i = 0; i < RANGE; ++i) {
      int c = q4 * RANGE + i;
      sv[i] = (c < T) ? __expf(sv[i] - mx) : 0.f;
      sm += sv[i];
    }
    sm += __shfl_xor(sm, 1);
    sm += __shfl_xor(sm, 2);
    const float inv = 1.f / sm;
    __syncthreads();
    #pragma unroll
    for (int i = 0; i < RANGE; ++i)
      ps[row * PS + q4 * RANGE + i] = tobf(sv[i] * inv);
  }
  __syncthreads();

  f32x4 oacc[4];
  #pragma unroll
  for (int mi = 0; mi < 4; ++mi) oacc[mi] = {0.f, 0.f, 0.f, 0.f};
  #pragma unroll
  for (int ks2 = 0; ks2 < TK; ++ks2) {
    short8 bb = *(const short8*)&vs[(wv * 16 + lr) * PS + ks2 * 32 + lg * 8];
    #pragma unroll
    for (int mi = 0; mi < 4; ++mi) {
      short8 a = *(const short8*)&ps[(mi * 16 + lr) * PS + ks2 * 32 + lg * 8];
      oacc[mi] = __builtin_amdgcn_mfma_f32_16x16x32_bf16(a, bb, oacc[mi], 0, 0, 0);
    }
  }

  const int dh = wv * 16 + lr;
  const size_t chb = (size_t)b * 512 + h * 64 + dh;
  #pragma unroll
  for (int mi = 0; mi < 4; ++mi) {
    const int t0 = mi * 16 + lg * 4;
    const size_t idx = chb * 64 + t0;
    f32x4 v = oacc[mi];
    if constexpr (RESBF) {
      const __hip_bfloat16* rb = (const __hip_bfloat16*)res + chb * T + t0;
      #pragma unroll
      for (int r = 0; r < 4; ++r) v[r] += frombf(rb[r]);
    } else {
      v += *(const f32x4*)&((const float*)res)[idx];
    }
    *(f32x4*)&out[idx] = v;
    if constexpr (WRITEXC) {
      #pragma unroll
      for (int r = 0; r < 4; ++r)
        xcout[((size_t)b * 64 + t0 + r) * 512 + (h << 6) + dh] = tobf(lrelu(v[r]));
    }
  }
}

// ---------------------------------------------------------------------------
// MFMA conv 3x3 SAME on 8x8, CIN=512 (validated round-7 structure).
// INBF: input is bf16 board-transposed Xc/Tc [b][cell][512], lrelu already
//       applied -> staging is coalesced uint4 copies + conflict-free b128
//       LDS writes (no cvt, no lrelu).
// OUTBF: write bf16 lrelu'd board-transposed Tc [b][cell][COUT] instead of
//        f32 [b][o][cell] (bit-identical values to old f32 path + re-cvt).
// ---------------------------------------------------------------------------
template <bool RMSOUT, bool RESADD, bool INBF, bool OUTBF>
__global__ __launch_bounds__(256) void conv_mfma2b(
    const void* __restrict__ xin,
    const __hip_bfloat16* __restrict__ W2,
    const float* __restrict__ bias,
    const float* __restrict__ nw,
    const float* __restrict__ res,
    void* __restrict__ outp,
    int COUT)
{
  const int ntc = COUT >> 8;
  const int b = blockIdx.x / ntc;
  const int nt = blockIdx.x - b * ntc;
  const int o0 = nt << 8;
  const int NJ = COUT >> 4;
  const int tid = threadIdx.x;
  const int lane = tid & 63, wv = tid >> 6;
  const int lr = lane & 15, lg = lane >> 4;

  __shared__ __hip_bfloat16 xt[2][100 * 72];  // 10x10 zero-bordered boards

  f32x4 acc[4][4];
  #pragma unroll
  for (int mi = 0; mi < 4; ++mi)
    #pragma unroll
    for (int ni = 0; ni < 4; ++ni) acc[mi][ni] = {0.f, 0.f, 0.f, 0.f};

  for (int i = tid; i < 7200; i += 256) { xt[0][i] = tobf(0.f); xt[1][i] = tobf(0.f); }

  // f32 staging mapping (INBF=false)
  f32x4 sreg[4];
  const int s_ci = tid >> 4;
  const int s_p4 = (tid & 15) << 2;
  const int s_row = (((s_p4 >> 3) + 1) * 10 + (s_p4 & 7) + 1) * 72;
  // bf16 staging mapping (INBF=true): 2 cells x 8 ch per thread, b128 moves
  uint4 sregb[2];
  const int c_cg = tid & 7;
  const int c_cell0 = tid >> 3;                    // 0..31 (+32 for second)
  const int c_lofs0 = (((c_cell0 >> 3) + 1) * 10 + (c_cell0 & 7) + 1) * 72 + c_cg * 8;
  const int c_cell1 = c_cell0 + 32;
  const int c_lofs1 = (((c_cell1 >> 3) + 1) * 10 + (c_cell1 & 7) + 1) * 72 + c_cg * 8;

  auto stage_load = [&](int cc_) {
    if constexpr (INBF) {
      const __hip_bfloat16* xbf = (const __hip_bfloat16*)xin;
      const __hip_bfloat16* p0 =
          xbf + ((size_t)b * 64 + c_cell0) * 512 + cc_ * 64 + c_cg * 8;
      sregb[0] = *(const uint4*)p0;
      sregb[1] = *(const uint4*)(p0 + 32 * 512);
    } else {
      const float* xf = (const float*)xin;
      const float* xb_ = xf + ((size_t)b * 512 + cc_ * 64 + s_ci) * 64 + s_p4;
      #pragma unroll
      for (int u = 0; u < 4; ++u) sreg[u] = *(const f32x4*)&xb_[u * 1024];
    }
  };
  auto stage_write = [&](int buf_) {
    if constexpr (INBF) {
      *(uint4*)&xt[buf_][c_lofs0] = sregb[0];
      *(uint4*)&xt[buf_][c_lofs1] = sregb[1];
    } else {
      #pragma unroll
      for (int u = 0; u < 4; ++u)
        #pragma unroll
        for (int j = 0; j < 4; ++j)
          xt[buf_][s_row + j * 72 + s_ci + u * 16] = tobf(lrelu(sreg[u][j]));
    }
  };

  stage_load(0);
  __syncthreads();            // zero-init visible before interior writes
  stage_write(0);
  __syncthreads();

  const int ojb2 = ((o0 >> 4) + wv * 4) * 2;

  for (int cc = 0; cc < 8; ++cc) {
    const int cur = cc & 1;
    if (cc < 7) stage_load(cc + 1);
    const __hip_bfloat16* xb = xt[cur];

    #pragma unroll
    for (int k = 0; k < 9; ++k) {
      const int dy = k / 3 - 1, dx = k - (k / 3) * 3 - 1;
      const int ii0 = (lr >> 3) + dy + 1;
      const int jj0 = (lr & 7) + dx + 1;
      const size_t slab = ((size_t)(cc * 9 + k) * NJ) * 2 + ojb2;
      short8 bv[2][4], av[2][4];
      #pragma unroll
      for (int ni = 0; ni < 4; ++ni)
        #pragma unroll
        for (int ks = 0; ks < 2; ++ks)
          bv[ks][ni] = *(const short8*)&W2[(slab + ni * 2 + ks) * 512 + lane * 8];
      #pragma unroll
      for (int ks = 0; ks < 2; ++ks)
        #pragma unroll
        for (int mi = 0; mi < 4; ++mi)
          av[ks][mi] = *(const short8*)&xb[((ii0 + mi * 2) * 10 + jj0) * 72 + ks * 32 + lg * 8];
      #pragma unroll
      for (int ks = 0; ks < 2; ++ks)
        #pragma unroll
        for (int mi = 0; mi < 4; ++mi)
          #pragma unroll
          for (int ni = 0; ni < 4; ++ni)
            acc[mi][ni] = __builtin_amdgcn_mfma_f32_16x16x32_bf16(
                av[ks][mi], bv[ks][ni], acc[mi][ni], 0, 0, 0);
    }
    if (cc < 7) stage_write(cur ^ 1);
    __syncthreads();
  }

  #pragma unroll
  for (int ni = 0; ni < 4; ++ni) {
    const int o = o0 + wv * 64 + ni * 16 + lr;
    const float bvs = bias[o];
    float sc = 1.f;
    if constexpr (RMSOUT) {
      float ssq = 0.f;
      #pragma unroll
      for (int mi = 0; mi < 4; ++mi)
        #pragma unroll
        for (int r = 0; r < 4; ++r) {
          float v = acc[mi][ni][r] + bvs;
          ssq += v * v;
        }
      ssq += __shfl_xor(ssq, 16);
      ssq += __shfl_xor(ssq, 32);
      sc = nw[0] * rsqrtf(ssq * (1.f / 64.f) + 1e-6f);
    }
    if constexpr (OUTBF) {
      __hip_bfloat16* tc = (__hip_bfloat16*)outp;
      #pragma unroll
      for (int mi = 0; mi < 4; ++mi)
        #pragma unroll
        for (int r = 0; r < 4; ++r) {
          int cell = mi * 16 + lg * 4 + r;
          tc[((size_t)b * 64 + cell) * COUT + o] =
              tobf(lrelu((acc[mi][ni][r] + bvs) * sc));
        }
    } else {
      float* outf = (float*)outp;
      #pragma unroll
      for (int mi = 0; mi < 4; ++mi) {
        size_t idx = ((size_t)b * COUT + o) * 64 + mi * 16 + lg * 4;
        f32x4 v;
        #pragma unroll
        for (int r = 0; r < 4; ++r) v[r] = (acc[mi][ni][r] + bvs) * sc;
        if constexpr (RESADD) v += *(const f32x4*)&res[idx];
        *(f32x4*)&outf[idx] = v;
      }
    }
  }
}

// ---------------------------------------------------------------------------
// Final VALID 8x8 conv: out[b] = sum_{c,p} lrelu(F1[b,c,p]) * w[c,p] + bias.
// ---------------------------------------------------------------------------
__global__ __launch_bounds__(256) void co2_kernel(
    const float* __restrict__ xf, const float* __restrict__ w,
    const float* __restrict__ cb, float* __restrict__ out)
{
  const int b = blockIdx.x, tid = threadIdx.x;
  const float* xb = xf + (size_t)b * 65536;
  float acc = 0.f;
  for (int i = tid; i < 65536; i += 256)
    acc += lrelu(xb[i]) * w[i];
  #pragma unroll
  for (int off = 32; off; off >>= 1) acc += __shfl_down(acc, off);
  __shared__ float red[4];
  if ((tid & 63) == 0) red[tid >> 6] = acc;
  __syncthreads();
  if (tid == 0) out[b] = red[0] + red[1] + red[2] + red[3] + cb[0];
}

// ---------------------------------------------------------------------------
extern "C" void kernel_launch(void* const* d_in, const int* in_sizes, int n_in,
                              void* d_out, int out_size, void* d_ws, size_t ws_size,
                              hipStream_t stream)
{
  const int*   fen        = (const int*)d_in[0];
  const int*   move       = (const int*)d_in[1];
  const float* rank_emb   = (const float*)d_in[2];
  const float* file_emb   = (const float*)d_in[3];
  const float* fen_emb    = (const float*)d_in[4];
  const float* move_emb   = (const float*)d_in[5];
  const float* abs_emb    = (const float*)d_in[6];
  const float* ln_w       = (const float*)d_in[7];
  const float* ln_b       = (const float*)d_in[8];
  const float* emb_qkv    = (const float*)d_in[9];
  const float* emb_norm_w = (const float*)d_in[10];
  const float* qkvw_in    = (const float*)d_in[11];
  const float* mha_norm_w = (const float*)d_in[12];
  const float* conv1_w    = (const float*)d_in[13];
  const float* conv1_b    = (const float*)d_in[14];
  const float* conv2_w    = (const float*)d_in[15];
  const float* conv2_b    = (const float*)d_in[16];
  const float* cb_norm_w  = (const float*)d_in[17];
  const float* out_norm_w = (const float*)d_in[18];
  const float* co1_w      = (const float*)d_in[19];
  const float* co1_b      = (const float*)d_in[20];
  const float* co2_w      = (const float*)d_in[21];
  const float* co2_b      = (const float*)d_in[22];
  float* out = (float*)d_out;

  char* base = (char*)d_ws;
  __hip_bfloat16* X71 = (__hip_bfloat16*)base;                       // 18,612,224 B
  float* X64 = (float*)(base + 18612224);                            // 33,554,432 B
  char* t1b  = base + 52166656;                                      // 67,108,864 B
  __hip_bfloat16* Wq0 = (__hip_bfloat16*)(base + 119275520);         //  1,572,864 B
  __hip_bfloat16* Wq2 = (__hip_bfloat16*)(base + 120848384);         // 12,582,912 B
  // T1-region aliases (phase-disjoint; see liveness map in header comment):
  __hip_bfloat16* qk71 = (__hip_bfloat16*)t1b;                       // 37,224,448
  __hip_bfloat16* vT71 = (__hip_bfloat16*)(t1b + 37224448);          // 20,971,520
  __hip_bfloat16* qk64 = (__hip_bfloat16*)t1b;                       // 33,554,432
  __hip_bfloat16* vT64 = (__hip_bfloat16*)(t1b + 33554432);          // 16,777,216
  __hip_bfloat16* Xc   = (__hip_bfloat16*)(t1b + 50331648);          // 16,777,216
  __hip_bfloat16* Tc   = (__hip_bfloat16*)t1b;                       // 16,777,216
  float* F1 = (float*)t1b;                                           // 67,108,864
  // conv weight slabs alias X71 region (dead after embedding attn):
  __hip_bfloat16* WcA = (__hip_bfloat16*)base;                 // up to 9.4MB (co1)
  __hip_bfloat16* WcB = (__hip_bfloat16*)(base + 4718592);     // 4,718,592 B

  // one-time QKV weight repacks
  repack_qkv_w0<<<3072, 256, 0, stream>>>(emb_qkv, Wq0);
  repack_qkv_w2<<<3072, 256, 0, stream>>>(qkvw_in, Wq2);

  // embeddings + layernorm -> X71 (bf16)
  build_ln_kernel<<<512, 256, 0, stream>>>(fen, move, rank_emb, file_emb,
                                           fen_emb, move_emb, abs_emb,
                                           ln_w, ln_b, X71);
  // embedding MHA (T=71): proj(+RMS) -> attn2 (residual = X71[:, :, :64])
  proj71_kernel<71, 80><<<1536, 256, 0, stream>>>(X71, Wq0, emb_norm_w, qk71, vT71);
  attn2_kernel<71, true, false><<<2048, 256, 0, stream>>>(qk71, vT71, X71, X64,
                                                          nullptr);

  for (int l = 0; l < 8; ++l) {
    repack_conv_pair<<<256, 256, 0, stream>>>(conv1_w + (size_t)l * 512 * 512 * 9,
                                              conv2_w + (size_t)l * 512 * 512 * 9,
                                              WcA, WcB);
    // conv1: RMS fused, bf16 transposed output Tc; input Xc (bf16) for l>=1
    if (l == 0)
      conv_mfma2b<true, false, false, true><<<512, 256, 0, stream>>>(
          X64, WcA, conv1_b + l * 512, cb_norm_w + l, nullptr, Tc, 512);
    else
      conv_mfma2b<true, false, true, true><<<512, 256, 0, stream>>>(
          Xc, WcA, conv1_b + l * 512, cb_norm_w + l, nullptr, Tc, 512);
    // conv2: bf16 input Tc, residual + f32 output into X64 (stream master)
    conv_mfma2b<false, true, true, false><<<512, 256, 0, stream>>>(
        Tc, WcB, conv2_b + l * 512, nullptr, X64, X64, 512);
    // MHA (T=64); attn writes Xc for the next layer's conv1 (not needed l=7)
    proj64_kernel<<<1536, 256, 0, stream>>>(X64, Wq2 + (size_t)l * 786432,
                                            mha_norm_w + l, qk64, vT64);
    if (l < 7)
      attn2_kernel<64, false, true><<<2048, 256, 0, stream>>>(qk64, vT64, X64,
                                                              X64, Xc);
    else
      attn2_kernel<64, false, false><<<2048, 256, 0, stream>>>(qk64, vT64, X64,
                                                               X64, nullptr);
  }

  // head: co1 (512->1024 SAME, RMS fused, f32 path) -> co2 (VALID 8x8)
  repack_conv_w2<<<256, 256, 0, stream>>>(co1_w, WcA, 1024);
  conv_mfma2b<true, false, false, false><<<1024, 256, 0, stream>>>(
      X64, WcA, co1_b, out_norm_w, nullptr, F1, 1024);
  co2_kernel<<<256, 256, 0, stream>>>(F1, co2_w, co2_b, out);
}